// Round 10
// baseline (153.439 us; speedup 1.0000x reference)
//
#include <hip/hip_runtime.h>
#include <hip/hip_bf16.h>

#define CC 256
#define NN 4096
#define CQ 32
#define LOG2E 1.4426950408889634f

using short4v = __attribute__((ext_vector_type(4))) short;
using short8 = __attribute__((ext_vector_type(8))) short;
using f32x4  = __attribute__((ext_vector_type(4))) float;

static __device__ __forceinline__ short f2bf(float f) {
  __hip_bfloat16 h = __float2bfloat16(f);
  return *reinterpret_cast<short*>(&h);
}

// ---------------------------------------------------------------------------
// Kernel 0: build Wf = W (Wq|Wk|Wv rows concat, 320x256) in FRAG-LINEAR bf16.
// (UNCHANGED, proven.)
// ---------------------------------------------------------------------------
__global__ __launch_bounds__(256) void prep_kernel(
    const float* __restrict__ Wq, const float* __restrict__ Wk,
    const float* __restrict__ Wv, __hip_bfloat16* __restrict__ Wf)
{
  int t = blockIdx.x*256 + threadIdx.x;          // 0..10239
  int lane = t & 63, frag = t >> 6;              // frag = tile*8 + kc
  int tile = frag >> 3, kc = frag & 7;
  int l15 = lane & 15, quad = lane >> 4;
  int R = tile*16 + l15;                         // output row 0..319
  int k0 = kc*32 + quad*8;
  const float* src;
  if (R < 32)       src = Wq + (size_t)R*CC + k0;
  else if (R < 64)  src = Wk + (size_t)(R-32)*CC + k0;
  else              src = Wv + (size_t)(R-64)*CC + k0;
  float4 a = *(const float4*)(src);
  float4 c = *(const float4*)(src + 4);
  short8 o;
  o[0]=f2bf(a.x); o[1]=f2bf(a.y); o[2]=f2bf(a.z); o[3]=f2bf(a.w);
  o[4]=f2bf(c.x); o[5]=f2bf(c.y); o[6]=f2bf(c.z); o[7]=f2bf(c.w);
  *reinterpret_cast<short8*>(reinterpret_cast<short*>(Wf) + (size_t)t*8) = o;
}

// ---------------------------------------------------------------------------
// Kernel 1: QKV via MFMA.  (UNCHANGED from R9: 512 threads x 512 blocks,
// frag-linear Xl, packed q/k stores, v repack.)
// ---------------------------------------------------------------------------
__global__ __launch_bounds__(512, 4) void qkv_kernel(
    const float* __restrict__ x, const __hip_bfloat16* __restrict__ Wf,
    const float* __restrict__ bq, const float* __restrict__ bk,
    const float* __restrict__ bv,
    __hip_bfloat16* __restrict__ qb, __hip_bfloat16* __restrict__ kb,
    __hip_bfloat16* __restrict__ vb)
{
  const int b  = blockIdx.y;
  const int n0 = blockIdx.x * 32;
  const int tid = threadIdx.x;
  const int lane = tid & 63;
  const int w = __builtin_amdgcn_readfirstlane(tid >> 6);  // wave 0..7
  const int l15 = lane & 15, quad = lane >> 4;

  __shared__ __align__(16) short Xl[16*64*8];     // frag-linear x, 16384 B
  __shared__ __align__(16) short Vr[8][16][32];   // per-wave repack, 8192 B

  // ---- stage x tile into frag-linear layout: 1024 slots x 16 B ----
  const float* xb = x + (size_t)b*CC*NN;
#pragma unroll
  for (int i = 0; i < 2; i++) {
    int s = tid + 512*i;                 // slot 0..1023
    int g = s >> 6, ln = s & 63;         // group (nr*8+kc), lane-slot
    int nr = g >> 3, kc = g & 7;
    int l15s = ln & 15, quads = ln >> 4;
    int n = n0 + nr*16 + l15s;
    int c0 = kc*32 + quads*8;
    float v[8];
#pragma unroll
    for (int j = 0; j < 8; j++) v[j] = xb[(size_t)(c0 + j)*NN + n];
    short8 sv;
#pragma unroll
    for (int j = 0; j < 8; j++) sv[j] = f2bf(v[j]);
    *reinterpret_cast<short8*>(&Xl[(size_t)s*8]) = sv;   // lane-linear 16 B
  }
  __syncthreads();

  const short* wfp = reinterpret_cast<const short*>(Wf);
  short* qb_s = reinterpret_cast<short*>(qb) + (size_t)b*NN*CQ;
  short* kb_s = reinterpret_cast<short*>(kb) + (size_t)b*NN*CQ;
  short* vb_s = reinterpret_cast<short*>(vb) + (size_t)b*CC*NN;

#define QKV_TILE(T) { \
    const int t_ = (T); \
    short8 Af[8]; \
    _Pragma("unroll") \
    for (int kc = 0; kc < 8; kc++) \
      Af[kc] = *(const short8*)(wfp + ((size_t)(t_*8 + kc)*64 + lane)*8); \
    f32x4 ac0 = {0.f,0.f,0.f,0.f}, ac1 = {0.f,0.f,0.f,0.f}; \
    _Pragma("unroll") \
    for (int kc = 0; kc < 8; kc++) { \
      short8 B0 = *(const short8*)(&Xl[((     kc)*64 + lane)*8]); \
      short8 B1 = *(const short8*)(&Xl[((8 +  kc)*64 + lane)*8]); \
      ac0 = __builtin_amdgcn_mfma_f32_16x16x32_bf16(Af[kc], B0, ac0, 0,0,0); \
      ac1 = __builtin_amdgcn_mfma_f32_16x16x32_bf16(Af[kc], B1, ac1, 0,0,0); \
    } \
    if (t_ < 2) { \
      int d0 = t_*16 + quad*4; \
      short4v p0, p1; \
      _Pragma("unroll") \
      for (int r = 0; r < 4; r++) { \
        float bb = bq[d0 + r]; \
        p0[r] = f2bf(LOG2E*(ac0[r] + bb)); \
        p1[r] = f2bf(LOG2E*(ac1[r] + bb)); \
      } \
      *(short4v*)(qb_s + (size_t)(n0      + l15)*CQ + d0) = p0; \
      *(short4v*)(qb_s + (size_t)(n0 + 16 + l15)*CQ + d0) = p1; \
    } else if (t_ < 4) { \
      int d0 = (t_-2)*16 + quad*4; \
      short4v p0, p1; \
      _Pragma("unroll") \
      for (int r = 0; r < 4; r++) { \
        float bb = bk[d0 + r]; \
        p0[r] = f2bf(ac0[r] + bb); \
        p1[r] = f2bf(ac1[r] + bb); \
      } \
      *(short4v*)(kb_s + (size_t)(n0      + l15)*CQ + d0) = p0; \
      *(short4v*)(kb_s + (size_t)(n0 + 16 + l15)*CQ + d0) = p1; \
    } else { \
      int rv0 = (t_-4)*16; \
      _Pragma("unroll") \
      for (int r = 0; r < 4; r++) { \
        float bb = bv[rv0 + quad*4 + r]; \
        Vr[w][quad*4 + r][     l15] = f2bf(ac0[r] + bb); \
        Vr[w][quad*4 + r][16 + l15] = f2bf(ac1[r] + bb); \
      } \
      int row = lane >> 2, cb = (lane & 3)*8; \
      short8 tv = *(const short8*)(&Vr[w][row][cb]); \
      *(short8*)(vb_s + (size_t)(rv0 + row)*NN + n0 + cb) = tv; \
    } }

  QKV_TILE(w);
  QKV_TILE(8 + w);
  if (w < 4) { QKV_TILE(16 + w); }
#undef QKV_TILE
}

// ---------------------------------------------------------------------------
// Kernel 2: attn, R9's 16-wave schedule with FRAG-LINEAR Vs/Ps.
// LDS unit (grp, mcol, l15) -> 16B slot ((grp*8 + mcol)*16 + l15):
//   av read (wave sg,mh; cg): contiguous 1 KB at ((sg*4+cg)*8 + mh*4)*16,
//   ap read (wave ph,mh; ng): contiguous 1 KB at ((ph*2+ng)*8 + mh*4)*16,
//   -> base + lane*16B, zero bank conflicts (same pattern as qkv's Xl).
// Staging writes land as 2x16B units (~2-way banks, free).  Pure layout
// change vs R9: same traffic, same MFMA order, bit-identical numerics.
// LDS 47.1 -> 41 KB.
// ---------------------------------------------------------------------------
__global__ __launch_bounds__(1024, 4) void attn_kernel(
    const __hip_bfloat16* __restrict__ qb, const __hip_bfloat16* __restrict__ kb,
    const __hip_bfloat16* __restrict__ vb,
    const float* __restrict__ x, const float* __restrict__ gamma,
    float* __restrict__ out)
{
  const int Bk = blockIdx.x;
  const int b = (Bk & 7) >> 1;                       // 2 XCDs per batch
  const int n0 = ((Bk >> 3)*2 + (Bk & 1)) * 64;      // n-tile 0..63
  const int tid = threadIdx.x;
  const int lane = tid & 63;
  const int w = __builtin_amdgcn_readfirstlane(tid >> 6);   // 0..15
  const int sg = w & 3;                               // S row-group / c-strip
  const int mh = (w >> 2) & 1;                        // m-half (PV K-range)
  const int ph = w >> 3;                              // m-16-col / n-half
  const int l15 = lane & 15, quad = lane >> 4;
  const int mbase = mh*32 + ph*16;                    // S column group

  __shared__ __align__(16) short Vsf[16*8*16*8];   // frag-linear V, 32768 B
  __shared__ __align__(16) short Psf[ 4*8*16*8];   // frag-linear P,  8192 B
  __shared__ float Lbuf[4][64];

  const short* qbase = (const short*)qb + (size_t)b*NN*CQ;
  const short* kbase = (const short*)kb + (size_t)b*NN*CQ;
  const short* vbase = (const short*)vb + (size_t)b*CC*NN;

  short8 aq = *(const short8*)(qbase + (size_t)(n0 + sg*16 + l15)*CQ + quad*8);

  // V staging: thread covers row vr, quarter sh (32 B = units sh*2, sh*2+1)
  const int vr = tid >> 2, sh = tid & 3;
  short* vdst0 = &Vsf[(((vr >> 4)*8 + sh*2    )*16 + (vr & 15))*8];
  short* vdst1 = &Vsf[(((vr >> 4)*8 + sh*2 + 1)*16 + (vr & 15))*8];

  // Ps write base: col = mbase + l15 -> unit mcol = col>>3, sub = col&7
  const int pcol = mbase + l15;
  short* pdst = &Psf[((sg*8 + (pcol >> 3))*16 + quad*4)*8 + (pcol & 7)];

  short8 vfa, vfb, kf;
  vfa = *(const short8*)(vbase + (size_t)vr*NN + sh*16);
  vfb = *(const short8*)(vbase + (size_t)vr*NN + sh*16 + 8);
  kf  = *(const short8*)(kbase + (size_t)(mbase + l15)*CQ + quad*8);
  *(short8*)(vdst0) = vfa;
  *(short8*)(vdst1) = vfb;

  f32x4 acc[4][2];
#pragma unroll
  for (int cg = 0; cg < 4; cg++)
#pragma unroll
    for (int ng = 0; ng < 2; ng++) acc[cg][ng] = (f32x4){0.f,0.f,0.f,0.f};
  float lsum[4] = {0.f,0.f,0.f,0.f};

  __syncthreads();

  for (int T = 0; T < 64; T++) {
    // prefetch tile T+1 into regs
    short8 nva, nvb, nk;
    if (T < 63) {
      const short* vp = vbase + (size_t)vr*NN + (T+1)*64 + sh*16;
      nva = *(const short8*)(vp);
      nvb = *(const short8*)(vp + 8);
      nk  = *(const short8*)(kbase + (size_t)((T+1)*64 + mbase + l15)*CQ + quad*8);
    }

    // S' for rows sg*16.., m-cols mbase..mbase+16
    f32x4 z = {0.f,0.f,0.f,0.f};
    f32x4 S = __builtin_amdgcn_mfma_f32_16x16x32_bf16(aq, kf, z, 0,0,0);
#pragma unroll
    for (int r = 0; r < 4; r++) {
      float e = __builtin_amdgcn_exp2f(S[r]);
      lsum[r] += e;
      pdst[r*8] = f2bf(e);
    }
    __syncthreads();   // Ps(T) + Vs(T) visible to all

    short8 ap0 = *(const short8*)(&Psf[((((ph*2    )*8 + mh*4)*16) + lane)*8]);
    short8 ap1 = *(const short8*)(&Psf[((((ph*2 + 1)*8 + mh*4)*16) + lane)*8]);
#pragma unroll
    for (int cg = 0; cg < 4; cg++) {
      short8 av = *(const short8*)(&Vsf[((((sg*4 + cg)*8 + mh*4)*16) + lane)*8]);
      acc[cg][0] = __builtin_amdgcn_mfma_f32_16x16x32_bf16(av, ap0, acc[cg][0], 0,0,0);
      acc[cg][1] = __builtin_amdgcn_mfma_f32_16x16x32_bf16(av, ap1, acc[cg][1], 0,0,0);
    }
    __syncthreads();   // everyone done reading Vs/Ps of tile T

    if (T < 63) {
      *(short8*)(vdst0) = nva;
      *(short8*)(vdst1) = nvb;
      kf = nk;
    }
  }

  // ---- L: reduce over l15, publish per (mh, ph) ----
#pragma unroll
  for (int r = 0; r < 4; r++) {
    float s = lsum[r];
    s += __shfl_xor(s, 1); s += __shfl_xor(s, 2);
    s += __shfl_xor(s, 4); s += __shfl_xor(s, 8);
    if (l15 == 0) Lbuf[mh*2 + ph][sg*16 + quad*4 + r] = s;
  }

  // ---- combine mh halves of acc via LDS (2 rounds of 2 c-strips) ----
  float* poolf = reinterpret_cast<float*>(&Vsf[0]);   // 32 KB scratch
  __syncthreads();
#pragma unroll
  for (int g = 0; g < 2; g++) {
    if (mh == 1 && (sg >> 1) == g) {
#pragma unroll
      for (int cg = 0; cg < 4; cg++)
#pragma unroll
        for (int ng = 0; ng < 2; ng++)
#pragma unroll
          for (int r = 0; r < 4; r++)
            poolf[(sg & 1)*4096 + (cg*16 + quad*4 + r)*64 + (ph*2 + ng)*16 + l15] = acc[cg][ng][r];
    }
    __syncthreads();
    if (mh == 0 && (sg >> 1) == g) {
#pragma unroll
      for (int cg = 0; cg < 4; cg++)
#pragma unroll
        for (int ng = 0; ng < 2; ng++)
#pragma unroll
          for (int r = 0; r < 4; r++)
            acc[cg][ng][r] += poolf[(sg & 1)*4096 + (cg*16 + quad*4 + r)*64 + (ph*2 + ng)*16 + l15];
    }
    __syncthreads();
  }

  // ---- epilogue (mh==0 waves): out = gamma*O/l + x ----
  if (mh == 0) {
    const float gm = gamma[0];
    float Lv[2];
#pragma unroll
    for (int ng = 0; ng < 2; ng++) {
      int n = (ph*2 + ng)*16 + l15;
      Lv[ng] = 1.0f / (Lbuf[0][n] + Lbuf[1][n] + Lbuf[2][n] + Lbuf[3][n]);
    }
#pragma unroll
    for (int cg = 0; cg < 4; cg++) {
#pragma unroll
      for (int ng = 0; ng < 2; ng++) {
#pragma unroll
        for (int r = 0; r < 4; r++) {
          size_t idx = ((size_t)b*CC + sg*64 + cg*16 + quad*4 + r)*NN + n0 + (ph*2 + ng)*16 + l15;
          out[idx] = gm * acc[cg][ng][r] * Lv[ng] + x[idx];
        }
      }
    }
  }
}

// ---------------------------------------------------------------------------
extern "C" void kernel_launch(void* const* d_in, const int* in_sizes, int n_in,
                              void* d_out, int out_size, void* d_ws, size_t ws_size,
                              hipStream_t stream) {
  const float* x     = (const float*)d_in[0];
  const float* Wq    = (const float*)d_in[1];
  const float* bq    = (const float*)d_in[2];
  const float* Wk    = (const float*)d_in[3];
  const float* bk    = (const float*)d_in[4];
  const float* Wv    = (const float*)d_in[5];
  const float* bv    = (const float*)d_in[6];
  const float* gamma = (const float*)d_in[7];
  float* out = (float*)d_out;

  char* ws = (char*)d_ws;
  if (ws_size < (11u << 20)) return;
  __hip_bfloat16* qb = (__hip_bfloat16*)(ws);                 // [B][N][32]  1 MB
  __hip_bfloat16* kb = (__hip_bfloat16*)(ws + (1u << 20));    // [B][N][32]  1 MB
  __hip_bfloat16* vb = (__hip_bfloat16*)(ws + (2u << 20));    // [B][C][N]   8 MB
  __hip_bfloat16* Wf = (__hip_bfloat16*)(ws + (10u << 20));   // frag-linear 160 KB

  prep_kernel<<<dim3(40), 256, 0, stream>>>(Wq, Wk, Wv, Wf);
  qkv_kernel<<<dim3(128, 4), 512, 0, stream>>>(x, Wf, bq, bk, bv, qb, kb, vb);
  attn_kernel<<<dim3(256), 1024, 0, stream>>>(qb, kb, vb, x, gamma, out);
}

// Round 11
// 149.633 us; speedup vs baseline: 1.0254x; 1.0254x over previous
//
#include <hip/hip_runtime.h>
#include <hip/hip_bf16.h>

#define CC 256
#define NN 4096
#define CQ 32
#define LOG2E 1.4426950408889634f

using short4v = __attribute__((ext_vector_type(4))) short;
using short8 = __attribute__((ext_vector_type(8))) short;
using f32x4  = __attribute__((ext_vector_type(4))) float;

static __device__ __forceinline__ short f2bf(float f) {
  __hip_bfloat16 h = __float2bfloat16(f);
  return *reinterpret_cast<short*>(&h);
}

// Workgroup barrier WITHOUT the vmcnt(0) drain __syncthreads forces:
// LDS ops are fenced (lgkmcnt(0) + compiler memory fence + sched pin),
// but global prefetch loads stay in flight across it (counted wait at use).
#define LDS_BARRIER() do {                                      \
    asm volatile("s_waitcnt lgkmcnt(0)" ::: "memory");          \
    __builtin_amdgcn_sched_barrier(0);                          \
    __builtin_amdgcn_s_barrier();                               \
    __builtin_amdgcn_sched_barrier(0);                          \
  } while (0)

// ---------------------------------------------------------------------------
// Kernel 0: build Wf = W (Wq|Wk|Wv rows concat, 320x256) in FRAG-LINEAR bf16.
// (UNCHANGED, proven.)
// ---------------------------------------------------------------------------
__global__ __launch_bounds__(256) void prep_kernel(
    const float* __restrict__ Wq, const float* __restrict__ Wk,
    const float* __restrict__ Wv, __hip_bfloat16* __restrict__ Wf)
{
  int t = blockIdx.x*256 + threadIdx.x;          // 0..10239
  int lane = t & 63, frag = t >> 6;              // frag = tile*8 + kc
  int tile = frag >> 3, kc = frag & 7;
  int l15 = lane & 15, quad = lane >> 4;
  int R = tile*16 + l15;                         // output row 0..319
  int k0 = kc*32 + quad*8;
  const float* src;
  if (R < 32)       src = Wq + (size_t)R*CC + k0;
  else if (R < 64)  src = Wk + (size_t)(R-32)*CC + k0;
  else              src = Wv + (size_t)(R-64)*CC + k0;
  float4 a = *(const float4*)(src);
  float4 c = *(const float4*)(src + 4);
  short8 o;
  o[0]=f2bf(a.x); o[1]=f2bf(a.y); o[2]=f2bf(a.z); o[3]=f2bf(a.w);
  o[4]=f2bf(c.x); o[5]=f2bf(c.y); o[6]=f2bf(c.z); o[7]=f2bf(c.w);
  *reinterpret_cast<short8*>(reinterpret_cast<short*>(Wf) + (size_t)t*8) = o;
}

// ---------------------------------------------------------------------------
// Kernel 1: QKV via MFMA.  (UNCHANGED from R9.)
// ---------------------------------------------------------------------------
__global__ __launch_bounds__(512, 4) void qkv_kernel(
    const float* __restrict__ x, const __hip_bfloat16* __restrict__ Wf,
    const float* __restrict__ bq, const float* __restrict__ bk,
    const float* __restrict__ bv,
    __hip_bfloat16* __restrict__ qb, __hip_bfloat16* __restrict__ kb,
    __hip_bfloat16* __restrict__ vb)
{
  const int b  = blockIdx.y;
  const int n0 = blockIdx.x * 32;
  const int tid = threadIdx.x;
  const int lane = tid & 63;
  const int w = __builtin_amdgcn_readfirstlane(tid >> 6);  // wave 0..7
  const int l15 = lane & 15, quad = lane >> 4;

  __shared__ __align__(16) short Xl[16*64*8];     // frag-linear x, 16384 B
  __shared__ __align__(16) short Vr[8][16][32];   // per-wave repack, 8192 B

  // ---- stage x tile into frag-linear layout: 1024 slots x 16 B ----
  const float* xb = x + (size_t)b*CC*NN;
#pragma unroll
  for (int i = 0; i < 2; i++) {
    int s = tid + 512*i;                 // slot 0..1023
    int g = s >> 6, ln = s & 63;         // group (nr*8+kc), lane-slot
    int nr = g >> 3, kc = g & 7;
    int l15s = ln & 15, quads = ln >> 4;
    int n = n0 + nr*16 + l15s;
    int c0 = kc*32 + quads*8;
    float v[8];
#pragma unroll
    for (int j = 0; j < 8; j++) v[j] = xb[(size_t)(c0 + j)*NN + n];
    short8 sv;
#pragma unroll
    for (int j = 0; j < 8; j++) sv[j] = f2bf(v[j]);
    *reinterpret_cast<short8*>(&Xl[(size_t)s*8]) = sv;   // lane-linear 16 B
  }
  __syncthreads();

  const short* wfp = reinterpret_cast<const short*>(Wf);
  short* qb_s = reinterpret_cast<short*>(qb) + (size_t)b*NN*CQ;
  short* kb_s = reinterpret_cast<short*>(kb) + (size_t)b*NN*CQ;
  short* vb_s = reinterpret_cast<short*>(vb) + (size_t)b*CC*NN;

#define QKV_TILE(T) { \
    const int t_ = (T); \
    short8 Af[8]; \
    _Pragma("unroll") \
    for (int kc = 0; kc < 8; kc++) \
      Af[kc] = *(const short8*)(wfp + ((size_t)(t_*8 + kc)*64 + lane)*8); \
    f32x4 ac0 = {0.f,0.f,0.f,0.f}, ac1 = {0.f,0.f,0.f,0.f}; \
    _Pragma("unroll") \
    for (int kc = 0; kc < 8; kc++) { \
      short8 B0 = *(const short8*)(&Xl[((     kc)*64 + lane)*8]); \
      short8 B1 = *(const short8*)(&Xl[((8 +  kc)*64 + lane)*8]); \
      ac0 = __builtin_amdgcn_mfma_f32_16x16x32_bf16(Af[kc], B0, ac0, 0,0,0); \
      ac1 = __builtin_amdgcn_mfma_f32_16x16x32_bf16(Af[kc], B1, ac1, 0,0,0); \
    } \
    if (t_ < 2) { \
      int d0 = t_*16 + quad*4; \
      short4v p0, p1; \
      _Pragma("unroll") \
      for (int r = 0; r < 4; r++) { \
        float bb = bq[d0 + r]; \
        p0[r] = f2bf(LOG2E*(ac0[r] + bb)); \
        p1[r] = f2bf(LOG2E*(ac1[r] + bb)); \
      } \
      *(short4v*)(qb_s + (size_t)(n0      + l15)*CQ + d0) = p0; \
      *(short4v*)(qb_s + (size_t)(n0 + 16 + l15)*CQ + d0) = p1; \
    } else if (t_ < 4) { \
      int d0 = (t_-2)*16 + quad*4; \
      short4v p0, p1; \
      _Pragma("unroll") \
      for (int r = 0; r < 4; r++) { \
        float bb = bk[d0 + r]; \
        p0[r] = f2bf(ac0[r] + bb); \
        p1[r] = f2bf(ac1[r] + bb); \
      } \
      *(short4v*)(kb_s + (size_t)(n0      + l15)*CQ + d0) = p0; \
      *(short4v*)(kb_s + (size_t)(n0 + 16 + l15)*CQ + d0) = p1; \
    } else { \
      int rv0 = (t_-4)*16; \
      _Pragma("unroll") \
      for (int r = 0; r < 4; r++) { \
        float bb = bv[rv0 + quad*4 + r]; \
        Vr[w][quad*4 + r][     l15] = f2bf(ac0[r] + bb); \
        Vr[w][quad*4 + r][16 + l15] = f2bf(ac1[r] + bb); \
      } \
      int row = lane >> 2, cb = (lane & 3)*8; \
      short8 tv = *(const short8*)(&Vr[w][row][cb]); \
      *(short8*)(vb_s + (size_t)(rv0 + row)*NN + n0 + cb) = tv; \
    } }

  QKV_TILE(w);
  QKV_TILE(8 + w);
  if (w < 4) { QKV_TILE(16 + w); }
#undef QKV_TILE
}

// ---------------------------------------------------------------------------
// Kernel 2: attn = R9's proven 16-wave schedule and LDS layout (68.0 us),
// with the two in-loop __syncthreads() replaced by LDS_BARRIER():
// raw s_barrier + lgkmcnt(0)-only fence.  __syncthreads forces a
// s_waitcnt vmcnt(0) drain at EVERY barrier (2x64 per block), which
// serialized each tile on its own global V/K prefetch latency.  With the
// LDS-only barrier the prefetch loads issued at tile start stay in flight
// across both barriers and get a counted wait at their ds_write use —
// a full tile of slack.  LDS ordering semantics are identical; numerics
// bit-identical (same values, same accumulation order).
// ---------------------------------------------------------------------------
__global__ __launch_bounds__(1024, 4) void attn_kernel(
    const __hip_bfloat16* __restrict__ qb, const __hip_bfloat16* __restrict__ kb,
    const __hip_bfloat16* __restrict__ vb,
    const float* __restrict__ x, const float* __restrict__ gamma,
    float* __restrict__ out)
{
  const int Bk = blockIdx.x;
  const int b = (Bk & 7) >> 1;                       // 2 XCDs per batch
  const int n0 = ((Bk >> 3)*2 + (Bk & 1)) * 64;      // n-tile 0..63
  const int tid = threadIdx.x;
  const int lane = tid & 63;
  const int w = __builtin_amdgcn_readfirstlane(tid >> 6);   // 0..15
  const int sg = w & 3;                               // S row-group / c-strip
  const int mh = (w >> 2) & 1;                        // m-half (PV K-range)
  const int ph = w >> 3;                              // m-16-col / n-half
  const int l15 = lane & 15, quad = lane >> 4;
  const int mbase = mh*32 + ph*16;                    // S column group

  __shared__ __align__(16) short Vs[256][72];   // [c][m 0..64], 36864 B
  __shared__ __align__(16) short Ps[64][72];    // [n][m 0..64], 9216 B
  __shared__ float Lbuf[4][64];

  const short* qbase = (const short*)qb + (size_t)b*NN*CQ;
  const short* kbase = (const short*)kb + (size_t)b*NN*CQ;
  const short* vbase = (const short*)vb + (size_t)b*CC*NN;

  short8 aq = *(const short8*)(qbase + (size_t)(n0 + sg*16 + l15)*CQ + quad*8);

  // V staging: thread covers row vr, quarter sh (16 shorts = 2 chunks)
  const int vr = tid >> 2, sh = tid & 3;

  short8 vfa, vfb, kf;
  vfa = *(const short8*)(vbase + (size_t)vr*NN + sh*16);
  vfb = *(const short8*)(vbase + (size_t)vr*NN + sh*16 + 8);
  kf  = *(const short8*)(kbase + (size_t)(mbase + l15)*CQ + quad*8);
  *(short8*)(&Vs[vr][sh*16    ]) = vfa;
  *(short8*)(&Vs[vr][sh*16 + 8]) = vfb;

  f32x4 acc[4][2];
#pragma unroll
  for (int cg = 0; cg < 4; cg++)
#pragma unroll
    for (int ng = 0; ng < 2; ng++) acc[cg][ng] = (f32x4){0.f,0.f,0.f,0.f};
  float lsum[4] = {0.f,0.f,0.f,0.f};

  __syncthreads();   // prologue barrier (full drain is fine here, once)

  for (int T = 0; T < 64; T++) {
    // prefetch tile T+1 into regs — these loads now survive both barriers
    short8 nva, nvb, nk;
    if (T < 63) {
      const short* vp = vbase + (size_t)vr*NN + (T+1)*64 + sh*16;
      nva = *(const short8*)(vp);
      nvb = *(const short8*)(vp + 8);
      nk  = *(const short8*)(kbase + (size_t)((T+1)*64 + mbase + l15)*CQ + quad*8);
    }

    // S' for rows sg*16.., m-cols mbase..mbase+16
    f32x4 z = {0.f,0.f,0.f,0.f};
    f32x4 S = __builtin_amdgcn_mfma_f32_16x16x32_bf16(aq, kf, z, 0,0,0);
#pragma unroll
    for (int r = 0; r < 4; r++) {
      float e = __builtin_amdgcn_exp2f(S[r]);
      lsum[r] += e;
      Ps[sg*16 + quad*4 + r][mbase + l15] = f2bf(e);
    }
    LDS_BARRIER();   // Ps(T) + Vs(T) visible to all; vmcnt NOT drained

    short8 ap0 = *(const short8*)(&Ps[(ph*2    )*16 + l15][mh*32 + quad*8]);
    short8 ap1 = *(const short8*)(&Ps[(ph*2 + 1)*16 + l15][mh*32 + quad*8]);
#pragma unroll
    for (int cg = 0; cg < 4; cg++) {
      short8 av = *(const short8*)(&Vs[sg*64 + cg*16 + l15][mh*32 + quad*8]);
      acc[cg][0] = __builtin_amdgcn_mfma_f32_16x16x32_bf16(av, ap0, acc[cg][0], 0,0,0);
      acc[cg][1] = __builtin_amdgcn_mfma_f32_16x16x32_bf16(av, ap1, acc[cg][1], 0,0,0);
    }
    LDS_BARRIER();   // all reads of Vs/Ps(T) done; vmcnt NOT drained

    if (T < 63) {
      // counted vmcnt wait lands here (ds_write uses), ~1 tile after issue
      *(short8*)(&Vs[vr][sh*16    ]) = nva;
      *(short8*)(&Vs[vr][sh*16 + 8]) = nvb;
      kf = nk;
    }
  }

  // ---- L: reduce over l15, publish per (mh, ph) ----
#pragma unroll
  for (int r = 0; r < 4; r++) {
    float s = lsum[r];
    s += __shfl_xor(s, 1); s += __shfl_xor(s, 2);
    s += __shfl_xor(s, 4); s += __shfl_xor(s, 8);
    if (l15 == 0) Lbuf[mh*2 + ph][sg*16 + quad*4 + r] = s;
  }

  // ---- combine mh halves of acc via LDS (2 rounds of 2 c-strips) ----
  float* poolf = reinterpret_cast<float*>(&Vs[0][0]);   // 32 KB scratch
  __syncthreads();
#pragma unroll
  for (int g = 0; g < 2; g++) {
    if (mh == 1 && (sg >> 1) == g) {
#pragma unroll
      for (int cg = 0; cg < 4; cg++)
#pragma unroll
        for (int ng = 0; ng < 2; ng++)
#pragma unroll
          for (int r = 0; r < 4; r++)
            poolf[(sg & 1)*4096 + (cg*16 + quad*4 + r)*64 + (ph*2 + ng)*16 + l15] = acc[cg][ng][r];
    }
    __syncthreads();
    if (mh == 0 && (sg >> 1) == g) {
#pragma unroll
      for (int cg = 0; cg < 4; cg++)
#pragma unroll
        for (int ng = 0; ng < 2; ng++)
#pragma unroll
          for (int r = 0; r < 4; r++)
            acc[cg][ng][r] += poolf[(sg & 1)*4096 + (cg*16 + quad*4 + r)*64 + (ph*2 + ng)*16 + l15];
    }
    __syncthreads();
  }

  // ---- epilogue (mh==0 waves): out = gamma*O/l + x ----
  if (mh == 0) {
    const float gm = gamma[0];
    float Lv[2];
#pragma unroll
    for (int ng = 0; ng < 2; ng++) {
      int n = (ph*2 + ng)*16 + l15;
      Lv[ng] = 1.0f / (Lbuf[0][n] + Lbuf[1][n] + Lbuf[2][n] + Lbuf[3][n]);
    }
#pragma unroll
    for (int cg = 0; cg < 4; cg++) {
#pragma unroll
      for (int ng = 0; ng < 2; ng++) {
#pragma unroll
        for (int r = 0; r < 4; r++) {
          size_t idx = ((size_t)b*CC + sg*64 + cg*16 + quad*4 + r)*NN + n0 + (ph*2 + ng)*16 + l15;
          out[idx] = gm * acc[cg][ng][r] * Lv[ng] + x[idx];
        }
      }
    }
  }
}

// ---------------------------------------------------------------------------
extern "C" void kernel_launch(void* const* d_in, const int* in_sizes, int n_in,
                              void* d_out, int out_size, void* d_ws, size_t ws_size,
                              hipStream_t stream) {
  const float* x     = (const float*)d_in[0];
  const float* Wq    = (const float*)d_in[1];
  const float* bq    = (const float*)d_in[2];
  const float* Wk    = (const float*)d_in[3];
  const float* bk    = (const float*)d_in[4];
  const float* Wv    = (const float*)d_in[5];
  const float* bv    = (const float*)d_in[6];
  const float* gamma = (const float*)d_in[7];
  float* out = (float*)d_out;

  char* ws = (char*)d_ws;
  if (ws_size < (11u << 20)) return;
  __hip_bfloat16* qb = (__hip_bfloat16*)(ws);                 // [B][N][32]  1 MB
  __hip_bfloat16* kb = (__hip_bfloat16*)(ws + (1u << 20));    // [B][N][32]  1 MB
  __hip_bfloat16* vb = (__hip_bfloat16*)(ws + (2u << 20));    // [B][C][N]   8 MB
  __hip_bfloat16* Wf = (__hip_bfloat16*)(ws + (10u << 20));   // frag-linear 160 KB

  prep_kernel<<<dim3(40), 256, 0, stream>>>(Wq, Wk, Wv, Wf);
  qkv_kernel<<<dim3(128, 4), 512, 0, stream>>>(x, Wf, bq, bk, bv, qb, kb, vb);
  attn_kernel<<<dim3(256), 1024, 0, stream>>>(qb, kb, vb, x, gamma, out);
}

// Round 12
// 144.282 us; speedup vs baseline: 1.0635x; 1.0371x over previous
//
#include <hip/hip_runtime.h>
#include <hip/hip_bf16.h>

#define CC 256
#define NN 4096
#define CQ 32
#define LOG2E 1.4426950408889634f

using short4v = __attribute__((ext_vector_type(4))) short;
using short8 = __attribute__((ext_vector_type(8))) short;
using f32x4  = __attribute__((ext_vector_type(4))) float;

static __device__ __forceinline__ short f2bf(float f) {
  __hip_bfloat16 h = __float2bfloat16(f);
  return *reinterpret_cast<short*>(&h);
}

// ---------------------------------------------------------------------------
// Kernel 0: build Wf = W (Wq|Wk|Wv rows concat, 320x256) in FRAG-LINEAR bf16.
// (UNCHANGED, proven.)
// ---------------------------------------------------------------------------
__global__ __launch_bounds__(256) void prep_kernel(
    const float* __restrict__ Wq, const float* __restrict__ Wk,
    const float* __restrict__ Wv, __hip_bfloat16* __restrict__ Wf)
{
  int t = blockIdx.x*256 + threadIdx.x;          // 0..10239
  int lane = t & 63, frag = t >> 6;              // frag = tile*8 + kc
  int tile = frag >> 3, kc = frag & 7;
  int l15 = lane & 15, quad = lane >> 4;
  int R = tile*16 + l15;                         // output row 0..319
  int k0 = kc*32 + quad*8;
  const float* src;
  if (R < 32)       src = Wq + (size_t)R*CC + k0;
  else if (R < 64)  src = Wk + (size_t)(R-32)*CC + k0;
  else              src = Wv + (size_t)(R-64)*CC + k0;
  float4 a = *(const float4*)(src);
  float4 c = *(const float4*)(src + 4);
  short8 o;
  o[0]=f2bf(a.x); o[1]=f2bf(a.y); o[2]=f2bf(a.z); o[3]=f2bf(a.w);
  o[4]=f2bf(c.x); o[5]=f2bf(c.y); o[6]=f2bf(c.z); o[7]=f2bf(c.w);
  *reinterpret_cast<short8*>(reinterpret_cast<short*>(Wf) + (size_t)t*8) = o;
}

// ---------------------------------------------------------------------------
// Kernel 1: QKV via MFMA.  (UNCHANGED from R9.)
// ---------------------------------------------------------------------------
__global__ __launch_bounds__(512, 4) void qkv_kernel(
    const float* __restrict__ x, const __hip_bfloat16* __restrict__ Wf,
    const float* __restrict__ bq, const float* __restrict__ bk,
    const float* __restrict__ bv,
    __hip_bfloat16* __restrict__ qb, __hip_bfloat16* __restrict__ kb,
    __hip_bfloat16* __restrict__ vb)
{
  const int b  = blockIdx.y;
  const int n0 = blockIdx.x * 32;
  const int tid = threadIdx.x;
  const int lane = tid & 63;
  const int w = __builtin_amdgcn_readfirstlane(tid >> 6);  // wave 0..7
  const int l15 = lane & 15, quad = lane >> 4;

  __shared__ __align__(16) short Xl[16*64*8];     // frag-linear x, 16384 B
  __shared__ __align__(16) short Vr[8][16][32];   // per-wave repack, 8192 B

  // ---- stage x tile into frag-linear layout: 1024 slots x 16 B ----
  const float* xb = x + (size_t)b*CC*NN;
#pragma unroll
  for (int i = 0; i < 2; i++) {
    int s = tid + 512*i;                 // slot 0..1023
    int g = s >> 6, ln = s & 63;         // group (nr*8+kc), lane-slot
    int nr = g >> 3, kc = g & 7;
    int l15s = ln & 15, quads = ln >> 4;
    int n = n0 + nr*16 + l15s;
    int c0 = kc*32 + quads*8;
    float v[8];
#pragma unroll
    for (int j = 0; j < 8; j++) v[j] = xb[(size_t)(c0 + j)*NN + n];
    short8 sv;
#pragma unroll
    for (int j = 0; j < 8; j++) sv[j] = f2bf(v[j]);
    *reinterpret_cast<short8*>(&Xl[(size_t)s*8]) = sv;   // lane-linear 16 B
  }
  __syncthreads();

  const short* wfp = reinterpret_cast<const short*>(Wf);
  short* qb_s = reinterpret_cast<short*>(qb) + (size_t)b*NN*CQ;
  short* kb_s = reinterpret_cast<short*>(kb) + (size_t)b*NN*CQ;
  short* vb_s = reinterpret_cast<short*>(vb) + (size_t)b*CC*NN;

#define QKV_TILE(T) { \
    const int t_ = (T); \
    short8 Af[8]; \
    _Pragma("unroll") \
    for (int kc = 0; kc < 8; kc++) \
      Af[kc] = *(const short8*)(wfp + ((size_t)(t_*8 + kc)*64 + lane)*8); \
    f32x4 ac0 = {0.f,0.f,0.f,0.f}, ac1 = {0.f,0.f,0.f,0.f}; \
    _Pragma("unroll") \
    for (int kc = 0; kc < 8; kc++) { \
      short8 B0 = *(const short8*)(&Xl[((     kc)*64 + lane)*8]); \
      short8 B1 = *(const short8*)(&Xl[((8 +  kc)*64 + lane)*8]); \
      ac0 = __builtin_amdgcn_mfma_f32_16x16x32_bf16(Af[kc], B0, ac0, 0,0,0); \
      ac1 = __builtin_amdgcn_mfma_f32_16x16x32_bf16(Af[kc], B1, ac1, 0,0,0); \
    } \
    if (t_ < 2) { \
      int d0 = t_*16 + quad*4; \
      short4v p0, p1; \
      _Pragma("unroll") \
      for (int r = 0; r < 4; r++) { \
        float bb = bq[d0 + r]; \
        p0[r] = f2bf(LOG2E*(ac0[r] + bb)); \
        p1[r] = f2bf(LOG2E*(ac1[r] + bb)); \
      } \
      *(short4v*)(qb_s + (size_t)(n0      + l15)*CQ + d0) = p0; \
      *(short4v*)(qb_s + (size_t)(n0 + 16 + l15)*CQ + d0) = p1; \
    } else if (t_ < 4) { \
      int d0 = (t_-2)*16 + quad*4; \
      short4v p0, p1; \
      _Pragma("unroll") \
      for (int r = 0; r < 4; r++) { \
        float bb = bk[d0 + r]; \
        p0[r] = f2bf(ac0[r] + bb); \
        p1[r] = f2bf(ac1[r] + bb); \
      } \
      *(short4v*)(kb_s + (size_t)(n0      + l15)*CQ + d0) = p0; \
      *(short4v*)(kb_s + (size_t)(n0 + 16 + l15)*CQ + d0) = p1; \
    } else { \
      int rv0 = (t_-4)*16; \
      _Pragma("unroll") \
      for (int r = 0; r < 4; r++) { \
        float bb = bv[rv0 + quad*4 + r]; \
        Vr[w][quad*4 + r][     l15] = f2bf(ac0[r] + bb); \
        Vr[w][quad*4 + r][16 + l15] = f2bf(ac1[r] + bb); \
      } \
      int row = lane >> 2, cb = (lane & 3)*8; \
      short8 tv = *(const short8*)(&Vr[w][row][cb]); \
      *(short8*)(vb_s + (size_t)(rv0 + row)*NN + n0 + cb) = tv; \
    } }

  QKV_TILE(w);
  QKV_TILE(8 + w);
  if (w < 4) { QKV_TILE(16 + w); }
#undef QKV_TILE
}

// ---------------------------------------------------------------------------
// Kernel 2: attn = R9's proven 16-wave schedule/layout/barriers (68.0 us),
// with SWAPPED-OPERAND S: S^T = mfma(kf, aq) gives each lane 4 values at
// CONSECUTIVE m-columns of one n-row -> single aligned ds_write_b64 into
// Ps[n][m], replacing 4 scalar ds_write_b16 (64 -> 16 LDS write instrs per
// tile per CU; the LDS pipe is the measured bottleneck at ~12 cyc/b128).
// Same dot products, same exp values; ap/av reads and PV MFMA order
// unchanged; lsum regroups its reduction (over quad via shfl_xor 16/32
// instead of over l15) — same sum, ulp-level order change.
// ---------------------------------------------------------------------------
__global__ __launch_bounds__(1024, 4) void attn_kernel(
    const __hip_bfloat16* __restrict__ qb, const __hip_bfloat16* __restrict__ kb,
    const __hip_bfloat16* __restrict__ vb,
    const float* __restrict__ x, const float* __restrict__ gamma,
    float* __restrict__ out)
{
  const int Bk = blockIdx.x;
  const int b = (Bk & 7) >> 1;                       // 2 XCDs per batch
  const int n0 = ((Bk >> 3)*2 + (Bk & 1)) * 64;      // n-tile 0..63
  const int tid = threadIdx.x;
  const int lane = tid & 63;
  const int w = __builtin_amdgcn_readfirstlane(tid >> 6);   // 0..15
  const int sg = w & 3;                               // S row-group / c-strip
  const int mh = (w >> 2) & 1;                        // m-half (PV K-range)
  const int ph = w >> 3;                              // m-16-col / n-half
  const int l15 = lane & 15, quad = lane >> 4;
  const int mbase = mh*32 + ph*16;                    // S column group

  __shared__ __align__(16) short Vs[256][72];   // [c][m 0..64], 36864 B
  __shared__ __align__(16) short Ps[64][72];    // [n][m 0..64], 9216 B
  __shared__ float Lbuf[4][64];

  const short* qbase = (const short*)qb + (size_t)b*NN*CQ;
  const short* kbase = (const short*)kb + (size_t)b*NN*CQ;
  const short* vbase = (const short*)vb + (size_t)b*CC*NN;

  short8 aq = *(const short8*)(qbase + (size_t)(n0 + sg*16 + l15)*CQ + quad*8);

  // V staging: thread covers row vr, quarter sh (16 shorts = 2 chunks)
  const int vr = tid >> 2, sh = tid & 3;

  // Ps write base for swapped-S: row n = sg*16 + l15, cols mbase+quad*4..+3
  short* pdst = &Ps[sg*16 + l15][mbase + quad*4];

  short8 vfa, vfb, kf;
  vfa = *(const short8*)(vbase + (size_t)vr*NN + sh*16);
  vfb = *(const short8*)(vbase + (size_t)vr*NN + sh*16 + 8);
  kf  = *(const short8*)(kbase + (size_t)(mbase + l15)*CQ + quad*8);
  *(short8*)(&Vs[vr][sh*16    ]) = vfa;
  *(short8*)(&Vs[vr][sh*16 + 8]) = vfb;

  f32x4 acc[4][2];
#pragma unroll
  for (int cg = 0; cg < 4; cg++)
#pragma unroll
    for (int ng = 0; ng < 2; ng++) acc[cg][ng] = (f32x4){0.f,0.f,0.f,0.f};
  float lsum = 0.f;   // partial sum for n-row sg*16+l15, m-cols mbase+quad*4..+3

  __syncthreads();

  for (int T = 0; T < 64; T++) {
    // prefetch tile T+1 into regs
    short8 nva, nvb, nk;
    if (T < 63) {
      const short* vp = vbase + (size_t)vr*NN + (T+1)*64 + sh*16;
      nva = *(const short8*)(vp);
      nvb = *(const short8*)(vp + 8);
      nk  = *(const short8*)(kbase + (size_t)((T+1)*64 + mbase + l15)*CQ + quad*8);
    }

    // S^T = K · Q^T: lane holds rows m = mbase+quad*4..+3, col n = sg*16+l15
    f32x4 z = {0.f,0.f,0.f,0.f};
    f32x4 S = __builtin_amdgcn_mfma_f32_16x16x32_bf16(kf, aq, z, 0,0,0);
    {
      short4v pk;
#pragma unroll
      for (int r = 0; r < 4; r++) {
        float e = __builtin_amdgcn_exp2f(S[r]);
        lsum += e;
        pk[r] = f2bf(e);
      }
      *(short4v*)(pdst) = pk;       // one ds_write_b64 (was 4x ds_write_b16)
    }
    __syncthreads();   // Ps(T) + Vs(T) visible to all

    short8 ap0 = *(const short8*)(&Ps[(ph*2    )*16 + l15][mh*32 + quad*8]);
    short8 ap1 = *(const short8*)(&Ps[(ph*2 + 1)*16 + l15][mh*32 + quad*8]);
#pragma unroll
    for (int cg = 0; cg < 4; cg++) {
      short8 av = *(const short8*)(&Vs[sg*64 + cg*16 + l15][mh*32 + quad*8]);
      acc[cg][0] = __builtin_amdgcn_mfma_f32_16x16x32_bf16(av, ap0, acc[cg][0], 0,0,0);
      acc[cg][1] = __builtin_amdgcn_mfma_f32_16x16x32_bf16(av, ap1, acc[cg][1], 0,0,0);
    }
    __syncthreads();   // everyone done reading Vs/Ps of tile T

    if (T < 63) {
      *(short8*)(&Vs[vr][sh*16    ]) = nva;
      *(short8*)(&Vs[vr][sh*16 + 8]) = nvb;
      kf = nk;
    }
  }

  // ---- L: lane holds partial for n = sg*16+l15; reduce over quad ----
  {
    float s = lsum;
    s += __shfl_xor(s, 16); s += __shfl_xor(s, 32);
    if (quad == 0) Lbuf[mh*2 + ph][sg*16 + l15] = s;
  }

  // ---- combine mh halves of acc via LDS (2 rounds of 2 c-strips) ----
  float* poolf = reinterpret_cast<float*>(&Vs[0][0]);   // 32 KB scratch
  __syncthreads();
#pragma unroll
  for (int g = 0; g < 2; g++) {
    if (mh == 1 && (sg >> 1) == g) {
#pragma unroll
      for (int cg = 0; cg < 4; cg++)
#pragma unroll
        for (int ng = 0; ng < 2; ng++)
#pragma unroll
          for (int r = 0; r < 4; r++)
            poolf[(sg & 1)*4096 + (cg*16 + quad*4 + r)*64 + (ph*2 + ng)*16 + l15] = acc[cg][ng][r];
    }
    __syncthreads();
    if (mh == 0 && (sg >> 1) == g) {
#pragma unroll
      for (int cg = 0; cg < 4; cg++)
#pragma unroll
        for (int ng = 0; ng < 2; ng++)
#pragma unroll
          for (int r = 0; r < 4; r++)
            acc[cg][ng][r] += poolf[(sg & 1)*4096 + (cg*16 + quad*4 + r)*64 + (ph*2 + ng)*16 + l15];
    }
    __syncthreads();
  }

  // ---- epilogue (mh==0 waves): out = gamma*O/l + x ----
  if (mh == 0) {
    const float gm = gamma[0];
    float Lv[2];
#pragma unroll
    for (int ng = 0; ng < 2; ng++) {
      int n = (ph*2 + ng)*16 + l15;
      Lv[ng] = 1.0f / (Lbuf[0][n] + Lbuf[1][n] + Lbuf[2][n] + Lbuf[3][n]);
    }
#pragma unroll
    for (int cg = 0; cg < 4; cg++) {
#pragma unroll
      for (int ng = 0; ng < 2; ng++) {
#pragma unroll
        for (int r = 0; r < 4; r++) {
          size_t idx = ((size_t)b*CC + sg*64 + cg*16 + quad*4 + r)*NN + n0 + (ph*2 + ng)*16 + l15;
          out[idx] = gm * acc[cg][ng][r] * Lv[ng] + x[idx];
        }
      }
    }
  }
}

// ---------------------------------------------------------------------------
extern "C" void kernel_launch(void* const* d_in, const int* in_sizes, int n_in,
                              void* d_out, int out_size, void* d_ws, size_t ws_size,
                              hipStream_t stream) {
  const float* x     = (const float*)d_in[0];
  const float* Wq    = (const float*)d_in[1];
  const float* bq    = (const float*)d_in[2];
  const float* Wk    = (const float*)d_in[3];
  const float* bk    = (const float*)d_in[4];
  const float* Wv    = (const float*)d_in[5];
  const float* bv    = (const float*)d_in[6];
  const float* gamma = (const float*)d_in[7];
  float* out = (float*)d_out;

  char* ws = (char*)d_ws;
  if (ws_size < (11u << 20)) return;
  __hip_bfloat16* qb = (__hip_bfloat16*)(ws);                 // [B][N][32]  1 MB
  __hip_bfloat16* kb = (__hip_bfloat16*)(ws + (1u << 20));    // [B][N][32]  1 MB
  __hip_bfloat16* vb = (__hip_bfloat16*)(ws + (2u << 20));    // [B][C][N]   8 MB
  __hip_bfloat16* Wf = (__hip_bfloat16*)(ws + (10u << 20));   // frag-linear 160 KB

  prep_kernel<<<dim3(40), 256, 0, stream>>>(Wq, Wk, Wv, Wf);
  qkv_kernel<<<dim3(128, 4), 512, 0, stream>>>(x, Wf, bq, bk, bv, qb, kb, vb);
  attn_kernel<<<dim3(256), 1024, 0, stream>>>(qb, kb, vb, x, gamma, out);
}